// Round 2
// baseline (1268.065 us; speedup 1.0000x reference)
//
#include <hip/hip_runtime.h>

// 4-layer LSTM (B=1024,T=512,H=64,G=256) + FC head.
// 64 blocks x 1024 threads: block = 16-row batch chunk; wave-group (4 waves) = layer.
// Layers pipelined INSIDE the block (skewed by 1 superstep per layer); all handoff via
// double-buffered swizzled LDS + one __syncthreads per superstep. No global handshake,
// no atomics, no d_ws use. bf16 MFMA 16x16x32, fp32 accum, c-state in registers.

#define TLEN  512
#define BATCH 1024
#define NCH   64

typedef __bf16 bf16x8 __attribute__((ext_vector_type(8)));
typedef float  f32x4  __attribute__((ext_vector_type(4)));

struct Params {
  const float* x;
  const float* wih[4];
  const float* whh[4];
  const float* bih[4];
  const float* bhh[4];
  const float* fc1w; const float* fc1b;
  const float* fc2w; const float* fc2b;
  float* out;
};

__device__ __forceinline__ bf16x8 bfzero() {
  union { unsigned long long u[2]; bf16x8 v; } z; z.u[0] = 0ull; z.u[1] = 0ull; return z.v;
}
__device__ __forceinline__ float fast_sigmoid(float x) {
  return __builtin_amdgcn_rcpf(1.f + __expf(-x));
}
__device__ __forceinline__ float fast_tanh(float x) {
  float e = __expf(2.f * x);
  return 1.f - 2.f * __builtin_amdgcn_rcpf(e + 1.f);
}

__global__ __launch_bounds__(1024, 4) void lstm_fused(Params p)
{
  const int chunk = blockIdx.x;      // batch chunk (16 rows)
  const int b0   = chunk * 16;
  const int tid  = threadIdx.x;
  const int wave = tid >> 6;
  const int L    = wave >> 2;        // layer = wave group
  const int w    = wave & 3;         // columns [16w,16w+16) of each gate
  const int lane = tid & 63;
  const int quad = lane >> 4;
  const int l15  = lane & 15;

  __shared__ __bf16 hbuf[2][4][16 * 64];  // [parity][layer][swizzled 16x64 h tile]
  __shared__ float  s_fc1w[32 * 64];
  __shared__ float  s_z[16 * 32];
  __shared__ float  s_fc1b[32];
  __shared__ float  s_fc2w[96];
  __shared__ float  s_fc2b[3];

  // ---- stage weight fragments into registers (bf16) ----
  bf16x8 whhf[4][2];
  bf16x8 wihf[4][2];
  float  bias[4];
  {
    const float* whh = p.whh[L];
    const float* wih = p.wih[L];
    const float* bih = p.bih[L];
    const float* bhh = p.bhh[L];
#pragma unroll
    for (int g = 0; g < 4; g++) {
      int n = g * 64 + w * 16 + l15;  // B-frag: lane&15 = n, k = 32q + quad*8 + j
      bias[g] = bih[n] + bhh[n];
#pragma unroll
      for (int q = 0; q < 2; q++) {
        const float* s = whh + n * 64 + q * 32 + quad * 8;
        bf16x8 f;
#pragma unroll
        for (int j = 0; j < 8; j++) f[j] = (__bf16)s[j];
        whhf[g][q] = f;
      }
      if (L == 0) {                   // w_ih_0 is (256,4): pad K to 32 with zeros
        bf16x8 f = bfzero();
        if (quad == 0) {
#pragma unroll
          for (int j = 0; j < 4; j++) f[j] = (__bf16)wih[n * 4 + j];
        }
        wihf[g][0] = f; wihf[g][1] = f;
      } else {
#pragma unroll
        for (int q = 0; q < 2; q++) {
          const float* s = wih + n * 64 + q * 32 + quad * 8;
          bf16x8 f;
#pragma unroll
          for (int j = 0; j < 8; j++) f[j] = (__bf16)s[j];
          wihf[g][q] = f;
        }
      }
    }
  }

  { // zero both parities of all layer h tiles (t=0 and pipeline-fill reads are zeros)
    int* hi = (int*)hbuf;
    for (int i = tid; i < 4096; i += 1024) hi[i] = 0;
  }
  float cst[4] = {0.f, 0.f, 0.f, 0.f};

  // prologue: x fragment for t=0 (layer-0 waves only; quad 0 holds the 4 K-values)
  bf16x8 xcur = bfzero();
  if (L == 0 && quad == 0) {
    const float4 xv = *(const float4*)(p.x + ((size_t)(b0 + l15) * TLEN) * 4);
    bf16x8 f = bfzero();
    f[0] = (__bf16)xv.x; f[1] = (__bf16)xv.y; f[2] = (__bf16)xv.z; f[3] = (__bf16)xv.w;
    xcur = f;
  }
  __syncthreads();

  for (int s = 0; s < TLEN + 3; s++) {
    const int t  = s - L;            // this wave-group's timestep
    const int pr = s & 1;            // read parity (written at superstep s-1)
    const int pw = pr ^ 1;           // write parity
    bf16x8 xnext = xcur;

    if ((unsigned)t < (unsigned)TLEN) {
      // input fragments (A-layout: lane&15 = batch row m, k = 32q + quad*8 + j)
      bf16x8 xf0, xf1;
      if (L == 0) {
        xf0 = xcur; xf1 = xcur;
      } else {
        const __bf16* src = hbuf[pr][L - 1];
        int sg0 = quad ^ (l15 & 7);
        int sg1 = (4 + quad) ^ (l15 & 7);
        xf0 = *(const bf16x8*)&src[l15 * 64 + sg0 * 8];
        xf1 = *(const bf16x8*)&src[l15 * 64 + sg1 * 8];
      }
      // own recurrent h fragments
      bf16x8 hf0, hf1;
      {
        const __bf16* src = hbuf[pr][L];
        int sg0 = quad ^ (l15 & 7);
        int sg1 = (4 + quad) ^ (l15 & 7);
        hf0 = *(const bf16x8*)&src[l15 * 64 + sg0 * 8];
        hf1 = *(const bf16x8*)&src[l15 * 64 + sg1 * 8];
      }

      // gates = bias + x@Wih^T + h@Whh^T (fp32 accum)
      f32x4 acc[4];
#pragma unroll
      for (int g = 0; g < 4; g++) { f32x4 a = {bias[g], bias[g], bias[g], bias[g]}; acc[g] = a; }
      if (L == 0) {
#pragma unroll
        for (int g = 0; g < 4; g++)
          acc[g] = __builtin_amdgcn_mfma_f32_16x16x32_bf16(xf0, wihf[g][0], acc[g], 0, 0, 0);
      } else {
#pragma unroll
        for (int g = 0; g < 4; g++) {
          acc[g] = __builtin_amdgcn_mfma_f32_16x16x32_bf16(xf0, wihf[g][0], acc[g], 0, 0, 0);
          acc[g] = __builtin_amdgcn_mfma_f32_16x16x32_bf16(xf1, wihf[g][1], acc[g], 0, 0, 0);
        }
      }
#pragma unroll
      for (int g = 0; g < 4; g++) {
        acc[g] = __builtin_amdgcn_mfma_f32_16x16x32_bf16(hf0, whhf[g][0], acc[g], 0, 0, 0);
        acc[g] = __builtin_amdgcn_mfma_f32_16x16x32_bf16(hf1, whhf[g][1], acc[g], 0, 0, 0);
      }

      // prefetch next x while MFMAs are in flight (layer 0 only)
      if (L == 0 && quad == 0 && t + 1 < TLEN) {
        const float4 xv = *(const float4*)(p.x + ((size_t)(b0 + l15) * TLEN + (t + 1)) * 4);
        bf16x8 f = bfzero();
        f[0] = (__bf16)xv.x; f[1] = (__bf16)xv.y; f[2] = (__bf16)xv.z; f[3] = (__bf16)xv.w;
        xnext = f;
      }

      // per-lane LSTM cell: lane holds (m = quad*4+r, col = w*16+l15) for all 4 gates
      const int col = w * 16 + l15;
      __bf16* dst = hbuf[pw][L];
#pragma unroll
      for (int r = 0; r < 4; r++) {
        float ig = fast_sigmoid(acc[0][r]);
        float fg = fast_sigmoid(acc[1][r]);
        float gg = fast_tanh(acc[2][r]);
        float og = fast_sigmoid(acc[3][r]);
        float c = fg * cst[r] + ig * gg;
        cst[r] = c;
        float h = og * fast_tanh(c);
        int m  = quad * 4 + r;
        int sg = (col >> 3) ^ (m & 7);
        dst[m * 64 + sg * 8 + (col & 7)] = (__bf16)h;
      }
    }

    __syncthreads();   // LDS-only drain: publishes hbuf[pw] to the next layer group
    xcur = xnext;
  }

  // ---- FC head + softmax. Final h (t=511, layer 3) was written at s=514 -> parity 1.
  for (int i = tid; i < 2048; i += 1024) s_fc1w[i] = p.fc1w[i];
  if (tid < 32) s_fc1b[tid] = p.fc1b[tid];
  if (tid < 96) s_fc2w[tid] = p.fc2w[tid];
  if (tid < 3)  s_fc2b[tid] = p.fc2b[tid];
  __syncthreads();
  if (tid < 512) {
    int m = tid >> 5, u = tid & 31;
    float sacc = s_fc1b[u];
    const float* wrow = &s_fc1w[u * 64];
    const __bf16* hfin = hbuf[1][3];
#pragma unroll
    for (int k = 0; k < 64; k++) {
      int sg = (k >> 3) ^ (m & 7);
      sacc += (float)hfin[m * 64 + sg * 8 + (k & 7)] * wrow[k];
    }
    s_z[m * 32 + u] = fmaxf(sacc, 0.f);
  }
  __syncthreads();
  if (tid < 16) {
    int m = tid;
    float lg[3];
#pragma unroll
    for (int v = 0; v < 3; v++) {
      float sv = s_fc2b[v];
#pragma unroll
      for (int u = 0; u < 32; u++) sv += s_z[m * 32 + u] * s_fc2w[v * 32 + u];
      lg[v] = sv;
    }
    float mx = fmaxf(lg[0], fmaxf(lg[1], lg[2]));
    float e0 = __expf(lg[0] - mx), e1 = __expf(lg[1] - mx), e2 = __expf(lg[2] - mx);
    float inv = 1.f / (e0 + e1 + e2);
    float* o = p.out + (size_t)(b0 + m) * 3;
    o[0] = e0 * inv; o[1] = e1 * inv; o[2] = e2 * inv;
  }
}

extern "C" void kernel_launch(void* const* d_in, const int* in_sizes, int n_in,
                              void* d_out, int out_size, void* d_ws, size_t ws_size,
                              hipStream_t stream)
{
  (void)in_sizes; (void)n_in; (void)out_size; (void)d_ws; (void)ws_size;
  Params p;
  p.x = (const float*)d_in[0];
  for (int l = 0; l < 4; l++) {
    p.wih[l] = (const float*)d_in[1 + 4 * l];
    p.whh[l] = (const float*)d_in[2 + 4 * l];
    p.bih[l] = (const float*)d_in[3 + 4 * l];
    p.bhh[l] = (const float*)d_in[4 + 4 * l];
  }
  p.fc1w = (const float*)d_in[17];
  p.fc1b = (const float*)d_in[18];
  p.fc2w = (const float*)d_in[19];
  p.fc2b = (const float*)d_in[20];
  p.out = (float*)d_out;

  hipLaunchKernelGGL(lstm_fused, dim3(NCH), dim3(1024), 0, stream, p);
}